// Round 2
// baseline (228.236 us; speedup 1.0000x reference)
//
#include <hip/hip_runtime.h>

// Derivative1D: y[b, i, c] = x[b, i+1, c] - x[b, i, c]
// x: (B=64, L=16384, C=32) fp32 contiguous; y: (B, L-1, C) fp32.
// Flattened per batch: out[r] = x[r + C] - x[r], r in [0, (L-1)*C).
// Pure HBM-streaming kernel. Roofline: ~268 MB traffic / 6.3 TB/s ~= 42 us.
//
// R2: 8 float4 per thread, register-buffered (16 independent dwordx4 loads
// in flight before stores), 64 blocks/batch x 64 batches = 4096 blocks.

constexpr int B = 64;
constexpr int L = 16384;
constexpr int C = 32;
constexpr int PER_BATCH = (L - 1) * C;        // 524256 floats per batch (out)
constexpr int PER_BATCH_V4 = PER_BATCH / 4;   // 131064 float4 per batch
constexpr int IN_PER_BATCH = L * C;           // 524288 floats per batch (in)
constexpr int V4_PER_THREAD = 8;
constexpr int BLOCK = 256;
constexpr int V4_PER_BLOCK = BLOCK * V4_PER_THREAD;                  // 2048
constexpr int BLOCKS_PER_BATCH = (PER_BATCH_V4 + V4_PER_BLOCK - 1) / V4_PER_BLOCK; // 64

__global__ __launch_bounds__(BLOCK) void deriv1d_kernel(const float* __restrict__ x,
                                                        float* __restrict__ out) {
    const int b = blockIdx.y;
    const int base4 = blockIdx.x * V4_PER_BLOCK + threadIdx.x;  // float4 idx in batch

    const float* xb = x + (size_t)b * IN_PER_BATCH;
    float* ob = out + (size_t)b * PER_BATCH;

    float4 a[V4_PER_THREAD];
    float4 n[V4_PER_THREAD];
    bool ok[V4_PER_THREAD];

    // Issue all loads first: 16 independent global_load_dwordx4 per thread.
#pragma unroll
    for (int k = 0; k < V4_PER_THREAD; ++k) {
        int r4 = base4 + k * BLOCK;
        ok[k] = (r4 < PER_BATCH_V4);
        int r = r4 * 4;
        if (ok[k]) {
            a[k] = *reinterpret_cast<const float4*>(xb + r);
            n[k] = *reinterpret_cast<const float4*>(xb + r + C);
        }
    }

#pragma unroll
    for (int k = 0; k < V4_PER_THREAD; ++k) {
        if (ok[k]) {
            int r = (base4 + k * BLOCK) * 4;
            float4 d;
            d.x = n[k].x - a[k].x;
            d.y = n[k].y - a[k].y;
            d.z = n[k].z - a[k].z;
            d.w = n[k].w - a[k].w;
            *reinterpret_cast<float4*>(ob + r) = d;
        }
    }
}

extern "C" void kernel_launch(void* const* d_in, const int* in_sizes, int n_in,
                              void* d_out, int out_size, void* d_ws, size_t ws_size,
                              hipStream_t stream) {
    const float* x = (const float*)d_in[0];
    float* out = (float*)d_out;

    dim3 grid(BLOCKS_PER_BATCH, B);  // (64, 64)
    dim3 block(BLOCK);
    deriv1d_kernel<<<grid, block, 0, stream>>>(x, out);
}